// Round 10
// baseline (199.379 us; speedup 1.0000x reference)
//
#include <hip/hip_runtime.h>
#include <hip/hip_bf16.h>
#include <stdint.h>

using bf16 = __hip_bfloat16;
typedef __attribute__((ext_vector_type(8))) short bf16x8;   // 8 bf16 = 4 VGPRs
typedef __attribute__((ext_vector_type(4))) float f32x4;

static __device__ __forceinline__ float b2f(short u) {
  union { float f; unsigned int i; } c;
  c.i = ((unsigned int)(unsigned short)u) << 16;
  return c.f;
}
static __device__ __forceinline__ short f2b(float f) {
  return (short)__bfloat16_as_ushort(__float2bfloat16(f));
}

static __device__ __forceinline__ void cfence() { asm volatile("" ::: "memory"); }
static __device__ __forceinline__ void bar()    { cfence(); __builtin_amdgcn_s_barrier(); cfence(); }

__device__ __forceinline__ void async16(const void* g, void* lds) {
  __builtin_amdgcn_global_load_lds(
      (const __attribute__((address_space(1))) void*)g,
      (__attribute__((address_space(3))) void*)lds, 16, 0, 0);
}

// ---------------------------------------------------------------------------
// Both Kron-expanded transposed weights in one dispatch.
// ---------------------------------------------------------------------------
__global__ void build_w(const float* __restrict__ phm,
                        const float* __restrict__ Wd,
                        const float* __restrict__ Wu,
                        bf16* __restrict__ wdT, bf16* __restrict__ wuT) {
  int idx = blockIdx.x * 256 + threadIdx.x;
  if (idx < 1024 * 1024) {
    int n = idx >> 11, k = idx & 2047;
    int r = n >> 7, s = n & 127;
    int p = k >> 9, q = k & 511;
    float v = 0.f;
#pragma unroll
    for (int i = 0; i < 4; ++i)
      v += phm[i * 16 + p * 4 + r] * Wd[i * 65536 + q * 128 + s];
    wdT[idx] = (bf16)v;
  } else {
    int jj = idx - 1024 * 1024;
    int d = jj >> 9, b = jj & 511;
    int r = d >> 9, s = d & 511;
    int p = b >> 7, q = b & 127;
    float v = 0.f;
#pragma unroll
    for (int i = 0; i < 4; ++i)
      v += phm[i * 16 + p * 4 + r] * Wu[i * 65536 + q * 512 + s];
    wuT[jj] = (bf16)v;
  }
}

// ---------------------------------------------------------------------------
// FUSED adapter kernel. Grid 256 x 512thr, 144KB LDS => exactly 1 block/CU,
// all blocks co-resident (safe spin protocol).
// Phase 1 (R9 gemm1f): P[ch] tile = x(f32, cast fused) @ wdT^T, rows rg*128.
// Arrival: release-fence + atomicAdd(cnt[rg]); last of 4 chunk-blocks reduces
//   P[0..3] (fixed order, deterministic) + b_down + relu -> z, sets flags[rg].
// Phase 2 (R9 gemm2): spin on flags for the 2 row-groups of its out-tile,
//   acquire-fence, then out tile = z @ wuT^T + b_up (f32, nontemporal).
// Cross-XCD safety: __threadfence release/acquire around all handoffs; XCD
//   mapping (bid&7) is locality-heuristic only, never correctness.
// ---------------------------------------------------------------------------
__global__ __launch_bounds__(512, 2)
void fused(const float* __restrict__ X, const bf16* __restrict__ wdT,
           const bf16* __restrict__ wuT, const float* __restrict__ bd,
           const float* __restrict__ bu, bf16* __restrict__ P,
           bf16* __restrict__ Z, float* __restrict__ OUT,
           int* __restrict__ cnt, int* __restrict__ flags) {
  __shared__ bf16 BIG[2][2][256 * 64];   // 128 KB
  __shared__ bf16 A1[128 * 64];          // 16 KB
  __shared__ int amLastSh;

  const int bid = blockIdx.x;
  const int x8 = bid & 7, j = bid >> 3;
  const int tid = threadIdx.x, lane = tid & 63, wave = tid >> 6;
  const int rl = lane & 15, sw = lane >> 4, sx = rl & 7;
  const int rg1 = x8 * 8 + (j & 7);      // phase-1 row group (128 rows)

  //==================== PHASE 1: chunk GEMM -> P =====================
  {
    const int ch = j >> 3;               // 0..3 K chunk
    const int bm = rg1 * 128;
    const int koff = ch * 512;
    bf16* __restrict__ Pc = P + (size_t)ch * (8192 * 512);

    const int wm  = (wave >> 2) * 64;
    const int wnn = (wave & 3) * 128;
    const int hB  = wnn >> 8;
    const int bb  = wnn & 255;

    const int arow = tid >> 2;
    const int ac0  = (tid & 3) * 16;
    const float* __restrict__ Xrow = X + (size_t)(bm + arow) * 2048 + koff + ac0;
    const int as0 = (tid & 3) * 2;

    f32x4 acc[4][8] = {};
    float4 av[4];

#define ISSUE_AV(tt)                                                          \
  { _Pragma("unroll")                                                         \
    for (int q = 0; q < 4; ++q)                                               \
      av[q] = *(const float4*)(Xrow + (size_t)(tt) * 64 + q * 4); }

#define WRITE_A()                                                             \
  {                                                                           \
    bf16x8 w0, w1;                                                            \
    _Pragma("unroll")                                                         \
    for (int e = 0; e < 4; ++e) {                                             \
      w0[e]     = f2b(((const float*)&av[0])[e]);                             \
      w0[e + 4] = f2b(((const float*)&av[1])[e]);                             \
      w1[e]     = f2b(((const float*)&av[2])[e]);                             \
      w1[e + 4] = f2b(((const float*)&av[3])[e]);                             \
    }                                                                         \
    *(bf16x8*)(&A1[arow * 64 + (((as0)     ^ (arow & 7)) * 8)]) = w0;         \
    *(bf16x8*)(&A1[arow * 64 + (((as0 + 1) ^ (arow & 7)) * 8)]) = w1;         \
  }

#define STAGE_BH(tt, h)                                                       \
  { _Pragma("unroll")                                                         \
    for (int is = 0; is < 4; ++is) {                                          \
      int idx = is * 512 + tid;                                               \
      int r = idx >> 3, sl = idx & 7;                                         \
      async16(wdT + (size_t)((h) * 256 + r) * 2048 + koff + (tt) * 64         \
                  + ((sl ^ (r & 7)) * 8),                                     \
              &BIG[(tt) & 1][h][idx * 8]);                                    \
    } }

    const int nt = 8;

    ISSUE_AV(0);
    STAGE_BH(0, 0); STAGE_BH(0, 1);
    asm volatile("s_waitcnt vmcnt(8)" ::: "memory");
    WRITE_A();
    ISSUE_AV(1);
    asm volatile("s_waitcnt vmcnt(4) lgkmcnt(0)" ::: "memory");
    bar();

    bf16x8 af[4][2], bfr[2][2];

    for (int t = 0; t < nt; ++t) {
      const int cur = t & 1;
      const bf16* __restrict__ Bcur = &BIG[cur][hB][0];

#define LDAF(m, ks) af[m][ks] = *(const bf16x8*)(&A1[(wm + (m)*16 + rl) * 64 + ((((ks)*4 + sw) ^ sx) * 8)])
#define LDBF(q, n, ks) bfr[q][ks] = *(const bf16x8*)(Bcur + (bb + (n)*16 + rl) * 64 + ((((ks)*4 + sw) ^ sx) * 8))
#define QUAD1(N0)                                                             \
  __builtin_amdgcn_s_setprio(1);                                              \
  _Pragma("unroll") for (int m = 0; m < 4; ++m)                               \
  _Pragma("unroll") for (int n = 0; n < 2; ++n)                               \
  _Pragma("unroll") for (int ks = 0; ks < 2; ++ks)                            \
    acc[m][(N0) + n] = __builtin_amdgcn_mfma_f32_16x16x32_bf16(               \
        af[m][ks], bfr[n][ks], acc[m][(N0) + n], 0, 0, 0);                    \
  __builtin_amdgcn_s_setprio(0);

      // P0
      LDAF(0, 0); LDAF(0, 1); LDAF(1, 0); LDAF(1, 1);
      LDAF(2, 0); LDAF(2, 1); LDAF(3, 0); LDAF(3, 1);
      LDBF(0, 0, 0); LDBF(0, 0, 1); LDBF(1, 1, 0); LDBF(1, 1, 1);
      cfence();
      if (t + 1 < nt) STAGE_BH(t + 1, 0);
      bar(); QUAD1(0); bar();
      // P1
      LDBF(0, 2, 0); LDBF(0, 2, 1); LDBF(1, 3, 0); LDBF(1, 3, 1);
      cfence();
      if (t + 1 < nt) STAGE_BH(t + 1, 1);
      bar(); QUAD1(2); bar();
      // P2
      LDBF(0, 4, 0); LDBF(0, 4, 1); LDBF(1, 5, 0); LDBF(1, 5, 1);
      cfence();
      bar(); QUAD1(4); bar();
      // P3
      LDBF(0, 6, 0); LDBF(0, 6, 1); LDBF(1, 7, 0); LDBF(1, 7, 1);
      cfence();
      if (t + 1 < nt) {
        asm volatile("s_waitcnt vmcnt(8)" ::: "memory");
        WRITE_A();
        if (t + 2 < nt) {
          ISSUE_AV(t + 2);
          asm volatile("s_waitcnt vmcnt(4) lgkmcnt(0)" ::: "memory");
        } else {
          asm volatile("s_waitcnt vmcnt(0) lgkmcnt(0)" ::: "memory");
        }
      }
      __builtin_amdgcn_sched_barrier(0);
      bar(); QUAD1(6);
      if (t + 1 < nt) bar();

#undef LDAF
#undef LDBF
#undef QUAD1
    }
#undef ISSUE_AV
#undef WRITE_A
#undef STAGE_BH

    // vectorized P epilogue (per-wave LDS transpose in BIG[0], disjoint from
    // final tile's reads in BIG[1])
    float* scr = (float*)(&BIG[0][0][0]) + wave * (16 * 128);
#pragma unroll
    for (int m = 0; m < 4; ++m) {
      int grow = bm + wm + m * 16;
#pragma unroll
      for (int n = 0; n < 8; ++n)
#pragma unroll
        for (int q = 0; q < 4; ++q)
          scr[(sw * 4 + q) * 128 + n * 16 + rl] = acc[m][n][q];
      asm volatile("s_waitcnt lgkmcnt(0)" ::: "memory");
#pragma unroll
      for (int p = 0; p < 4; ++p) {
        int row = p * 4 + sw;
        f32x4 a = *(const f32x4*)(scr + row * 128 + rl * 8);
        f32x4 b = *(const f32x4*)(scr + row * 128 + rl * 8 + 4);
        bf16x8 o;
#pragma unroll
        for (int e = 0; e < 4; ++e) { o[e] = f2b(a[e]); o[e + 4] = f2b(b[e]); }
        *(bf16x8*)(&Pc[(size_t)(grow + row) * 512 + wnn + rl * 8]) = o;
      }
      asm volatile("s_waitcnt lgkmcnt(0)" ::: "memory");
    }
  }

  //==================== arrival + last-arriver reduction ==============
  asm volatile("s_waitcnt vmcnt(0)" ::: "memory");
  __threadfence();                                   // release P
  if (tid == 0) {
    int old = atomicAdd(&cnt[rg1], 1);               // device scope
    amLastSh = (old == 3) ? 1 : 0;
  }
  __syncthreads();
  if (amLastSh) {
    __threadfence();                                 // acquire P
    const bf16x8* P8 = (const bf16x8*)P;
    bf16x8* Z8 = (bf16x8*)Z;
    const size_t CS = (size_t)8192 * 512 / 8;
    const size_t base = (size_t)rg1 * 128 * 64;
    for (int i = tid; i < 128 * 64; i += 512) {
      size_t idx = base + i;
      bf16x8 a = P8[idx], b = P8[idx + CS], c = P8[idx + 2 * CS], d = P8[idx + 3 * CS];
      int c0 = (i & 63) * 8;
      bf16x8 o;
#pragma unroll
      for (int e = 0; e < 8; ++e) {
        float t = b2f(a[e]) + b2f(b[e]) + b2f(c[e]) + b2f(d[e]) + bd[c0 + e];
        o[e] = f2b(t > 0.f ? t : 0.f);
      }
      Z8[idx] = o;
    }
    asm volatile("s_waitcnt vmcnt(0)" ::: "memory");
    __threadfence();                                 // release z
    if (tid == 0)
      __hip_atomic_store(&flags[rg1], 1, __ATOMIC_RELAXED, __HIP_MEMORY_SCOPE_AGENT);
  }

  //==================== PHASE 2: out tile = z @ wuT + b_up ============
  const int bx2 = x8 * 4 + (j & 3);      // 0..31 row tile (256 rows)
  const int by2 = j >> 2;                // 0..7  col tile (256 cols)
  if (tid == 0) {
    while (__hip_atomic_load(&flags[bx2 * 2], __ATOMIC_RELAXED,
                             __HIP_MEMORY_SCOPE_AGENT) == 0)
      __builtin_amdgcn_s_sleep(1);
    while (__hip_atomic_load(&flags[bx2 * 2 + 1], __ATOMIC_RELAXED,
                             __HIP_MEMORY_SCOPE_AGENT) == 0)
      __builtin_amdgcn_s_sleep(1);
  }
  __syncthreads();
  __threadfence();                                   // acquire z
  bar();

  {
    const int bm = bx2 * 256;
    const int bn = by2 * 256;
    const int wmh  = wave >> 2;
    const int wn2  = wave & 3;
    const int wnh  = wn2 >> 1;
    const int brow = (wn2 & 1) * 64;

    bf16* const A2 = &BIG[0][0][0];      // [2][2][128*64]
    bf16* const B2 = &BIG[1][0][0];
#define ASH2(buf, half) (A2 + ((buf) * 2 + (half)) * 8192)
#define BSH2(buf, half) (B2 + ((buf) * 2 + (half)) * 8192)

    f32x4 acc[8][4] = {};

#define STAGE_A2(tt, h)                                                       \
  { _Pragma("unroll")                                                         \
    for (int is = 0; is < 2; ++is) {                                          \
      int idx = is * 512 + tid;                                               \
      int r = idx >> 3, sl = idx & 7;                                         \
      async16(Z + (size_t)(bm + (h) * 128 + r) * 512 + (tt) * 64              \
                  + ((sl ^ (r & 7)) * 8),                                     \
              ASH2((tt) & 1, h) + idx * 8);                                   \
    } }
#define STAGE_B2(tt, h)                                                       \
  { _Pragma("unroll")                                                         \
    for (int is = 0; is < 2; ++is) {                                          \
      int idx = is * 512 + tid;                                               \
      int r = idx >> 3, sl = idx & 7;                                         \
      async16(wuT + (size_t)(bn + (h) * 128 + r) * 512 + (tt) * 64            \
                  + ((sl ^ (r & 7)) * 8),                                     \
              BSH2((tt) & 1, h) + idx * 8);                                   \
    } }

    const int nt = 8;

    STAGE_A2(0, 0); STAGE_A2(0, 1);
    STAGE_B2(0, 0); STAGE_B2(0, 1);
    STAGE_A2(1, 0); STAGE_A2(1, 1);
    asm volatile("s_waitcnt vmcnt(4)" ::: "memory");
    bar();

    bf16x8 af[8][2], bf[4][2];

    for (int t = 0; t < nt; ++t) {
      const int cur = t & 1;
      const bf16* __restrict__ Acur = ASH2(cur, wmh);
      const bf16* __restrict__ Bcur = BSH2(cur, wnh);

#define LDA2(m, ks) af[m][ks] = *(const bf16x8*)(Acur + ((m)*16 + rl) * 64 + ((((ks)*4 + sw) ^ sx) * 8))
#define LDB2(n, ks) bf[n][ks] = *(const bf16x8*)(Bcur + (brow + (n)*16 + rl) * 64 + ((((ks)*4 + sw) ^ sx) * 8))
#define QUAD2(M0, N0)                                                         \
  __builtin_amdgcn_s_setprio(1);                                              \
  _Pragma("unroll") for (int m = 0; m < 4; ++m)                               \
  _Pragma("unroll") for (int n = 0; n < 2; ++n)                               \
  _Pragma("unroll") for (int ks = 0; ks < 2; ++ks)                            \
    acc[(M0) + m][(N0) + n] = __builtin_amdgcn_mfma_f32_16x16x32_bf16(        \
        af[(M0) + m][ks], bf[(N0) + n][ks], acc[(M0) + m][(N0) + n], 0, 0, 0);\
  __builtin_amdgcn_s_setprio(0);

      // P0
      LDA2(0, 0); LDA2(0, 1); LDA2(1, 0); LDA2(1, 1);
      LDA2(2, 0); LDA2(2, 1); LDA2(3, 0); LDA2(3, 1);
      LDB2(0, 0); LDB2(0, 1); LDB2(1, 0); LDB2(1, 1);
      cfence();
      if (t + 1 < nt) STAGE_B2(t + 1, 0);
      bar(); QUAD2(0, 0); bar();
      // P1
      LDB2(2, 0); LDB2(2, 1); LDB2(3, 0); LDB2(3, 1);
      cfence();
      if (t + 1 < nt) STAGE_B2(t + 1, 1);
      bar(); QUAD2(0, 2); bar();
      // P2
      LDA2(4, 0); LDA2(4, 1); LDA2(5, 0); LDA2(5, 1);
      LDA2(6, 0); LDA2(6, 1); LDA2(7, 0); LDA2(7, 1);
      cfence();
      bar(); QUAD2(4, 0); bar();
      // P3
      if (t + 2 < nt) {
        STAGE_A2(t + 2, 0); STAGE_A2(t + 2, 1);
        asm volatile("s_waitcnt vmcnt(4)" ::: "memory");
      } else if (t + 1 < nt) {
        asm volatile("s_waitcnt vmcnt(0)" ::: "memory");
      }
      bar(); QUAD2(4, 2);
      if (t + 1 < nt) bar();

#undef LDA2
#undef LDB2
#undef QUAD2
    }
#undef STAGE_A2
#undef STAGE_B2

    // vectorized f32 epilogue: LDS transpose -> nontemporal f32x4 stores
    float* scr = (float*)A2 + wave * (16 * 68);
    const int r4 = lane >> 4;
    const int c4 = lane & 15;
#pragma unroll
    for (int m = 0; m < 8; ++m) {
      int grow = bm + wmh * 128 + m * 16;
#pragma unroll
      for (int n = 0; n < 4; ++n)
#pragma unroll
        for (int q = 0; q < 4; ++q)
          scr[(sw * 4 + q) * 68 + n * 16 + rl] =
              acc[m][n][q] + bu[bn + wn2 * 64 + n * 16 + rl];
      asm volatile("s_waitcnt lgkmcnt(0)" ::: "memory");
#pragma unroll
      for (int jj = 0; jj < 4; ++jj) {
        int row = jj * 4 + r4;
        f32x4 v = *(const f32x4*)(scr + row * 68 + c4 * 4);
        __builtin_nontemporal_store(
            v, (f32x4*)(&OUT[(size_t)(grow + row) * 2048 + bn + wn2 * 64 + c4 * 4]));
      }
      asm volatile("s_waitcnt lgkmcnt(0)" ::: "memory");
    }
#undef ASH2
#undef BSH2
  }
}

// ---------------------------------------------------------------------------
extern "C" void kernel_launch(void* const* d_in, const int* in_sizes, int n_in,
                              void* d_out, int out_size, void* d_ws, size_t ws_size,
                              hipStream_t stream) {
  const float* x      = (const float*)d_in[0];   // [8192,2048]
  const float* phm    = (const float*)d_in[1];   // [4,4,4]
  const float* W_down = (const float*)d_in[2];   // [4,512,128]
  const float* b_down = (const float*)d_in[3];   // [512]
  const float* W_up   = (const float*)d_in[4];   // [4,128,512]
  const float* b_up   = (const float*)d_in[5];   // [2048]
  float* out = (float*)d_out;                    // [8192,2048] f32

  const size_t MB = 1024 * 1024;
  char* ws = (char*)d_ws;
  bf16* wdT = (bf16*)(ws);                 //  2 MB  [512][2048]
  bf16* wuT = (bf16*)(ws + 2 * MB);        //  2 MB  [2048][512]
  bf16* z   = (bf16*)(ws + 4 * MB);        //  8 MB  [8192][512]
  bf16* P   = (bf16*)(ws + 12 * MB);       // 32 MB  4 x [8192][512] partials
  int*  sync = (int*)(ws + 44 * MB);       // 64 cnt + 64 flags

  // zero the sync area every launch (ws is poisoned 0xAA before timing!)
  hipMemsetAsync(sync, 0, 128 * sizeof(int), stream);

  build_w<<<dim3((2 * 1024 * 1024) / 256), dim3(256), 0, stream>>>(
      phm, W_down, W_up, wdT, wuT);

  fused<<<dim3(256), dim3(512), 0, stream>>>(
      x, wdT, wuT, b_down, b_up, P, z, out, sync, sync + 64);
}

// Round 11
// 130.905 us; speedup vs baseline: 1.5231x; 1.5231x over previous
//
#include <hip/hip_runtime.h>
#include <hip/hip_bf16.h>
#include <stdint.h>

using bf16 = __hip_bfloat16;
typedef __attribute__((ext_vector_type(8))) short bf16x8;   // 8 bf16 = 4 VGPRs
typedef __attribute__((ext_vector_type(4))) float f32x4;

static __device__ __forceinline__ float b2f(short u) {
  union { float f; unsigned int i; } c;
  c.i = ((unsigned int)(unsigned short)u) << 16;
  return c.f;
}
static __device__ __forceinline__ short f2b(float f) {
  return (short)__bfloat16_as_ushort(__float2bfloat16(f));
}

static __device__ __forceinline__ void cfence() { asm volatile("" ::: "memory"); }
static __device__ __forceinline__ void bar()    { cfence(); __builtin_amdgcn_s_barrier(); cfence(); }

// ---------------------------------------------------------------------------
// Both Kron-expanded transposed weights in one dispatch.
// ---------------------------------------------------------------------------
__global__ void build_w(const float* __restrict__ phm,
                        const float* __restrict__ Wd,
                        const float* __restrict__ Wu,
                        bf16* __restrict__ wdT, bf16* __restrict__ wuT) {
  int idx = blockIdx.x * 256 + threadIdx.x;
  if (idx < 1024 * 1024) {
    int n = idx >> 11, k = idx & 2047;
    int r = n >> 7, s = n & 127;
    int p = k >> 9, q = k & 511;
    float v = 0.f;
#pragma unroll
    for (int i = 0; i < 4; ++i)
      v += phm[i * 16 + p * 4 + r] * Wd[i * 65536 + q * 128 + s];
    wdT[idx] = (bf16)v;
  } else {
    int jj = idx - 1024 * 1024;
    int d = jj >> 9, b = jj & 511;
    int r = d >> 9, s = d & 511;
    int p = b >> 7, q = b & 127;
    float v = 0.f;
#pragma unroll
    for (int i = 0; i < 4; ++i)
      v += phm[i * 16 + p * 4 + r] * Wu[i * 65536 + q * 512 + s];
    wuT[jj] = (bf16)v;
  }
}

// ---------------------------------------------------------------------------
// z = relu(sum_c P[c] + b_down) -> bf16.   P: 4 x [8192][512] bf16 partials
// ---------------------------------------------------------------------------
__global__ void zred(const bf16* __restrict__ P, const float* __restrict__ bias,
                     bf16* __restrict__ z) {
  int i = blockIdx.x * 256 + threadIdx.x;
  const int NV = 8192 * 512 / 8;
  if (i >= NV) return;
  const size_t CS = (size_t)NV;
  bf16x8 v0 = ((const bf16x8*)P)[i];
  bf16x8 v1 = ((const bf16x8*)P)[i + CS];
  bf16x8 v2 = ((const bf16x8*)P)[i + 2 * CS];
  bf16x8 v3 = ((const bf16x8*)P)[i + 3 * CS];
  int c0 = (i * 8) & 511;
  bf16x8 o;
#pragma unroll
  for (int j = 0; j < 8; ++j) {
    float t = b2f(v0[j]) + b2f(v1[j]) + b2f(v2[j]) + b2f(v3[j]) + bias[c0 + j];
    o[j] = f2b(t > 0.f ? t : 0.f);
  }
  ((bf16x8*)z)[i] = o;
}

// ---------------------------------------------------------------------------
// GEMM1 (cast fused, split-K x4): P[ch] = x(f32) @ wdT^T, tile 128x256, BK=64.
// B DIRECT-TO-REG (per-lane 16B fragment loads from L2, dbuf ping-pong);
// A reg-staged f32->bf16 -> LDS dbuf (XOR slot swizzle). 1 barrier/iter.
// vmcnt ledger/iter: [av(t+1)x4, B(t+1)x8] -> mid vmcnt(8) (av landed);
// after ISSUE_AV(t+2): [Bx8, avx4] -> end vmcnt(4) (B landed). Never 0.
// grid 512: xcd=bid&7 owns 8 row-tiles x 4 chunks x 2 col-halves
// (x slice re-read via L2/L3; wdT 2MB L2-resident per XCD).
// ---------------------------------------------------------------------------
__global__ __launch_bounds__(512, 2)
void gemm1f(const float* __restrict__ X, const bf16* __restrict__ Wt,
            bf16* __restrict__ P) {
  constexpr int KTOT = 2048, NOUT = 512;
  __shared__ bf16 A1[2][128 * 64];     // 32 KB
  __shared__ float scr_[8 * 16 * 68];  // 34.8 KB epilogue scratch

  const int bid = blockIdx.x;
  const int xcd = bid & 7, w = bid >> 3;      // w 0..63
  const int bx = xcd * 8 + (w & 7);           // 0..63 row tile (128 rows)
  const int cc = w >> 3;                      // 0..7
  const int ch = cc & 3;                      // K chunk
  const int bn = (cc >> 2) * 256;             // col half
  const int bm = bx * 128;
  const int koff = ch * 512;
  bf16* __restrict__ Pc = P + (size_t)ch * (8192 * NOUT);

  const int tid = threadIdx.x, lane = tid & 63, wave = tid >> 6;
  const int wm = (wave >> 2) * 64;            // 2 M groups
  const int wn = (wave & 3) * 64;             // 4 N groups
  const int rl = lane & 15, sw = lane >> 4, sx = rl & 7;

  // A staging: thread -> row arow, 16 f32 at ac0
  const int arow = tid >> 2, ac0 = (tid & 3) * 16, as0 = (tid & 3) * 2;
  const float* __restrict__ Xrow = X + (size_t)(bm + arow) * KTOT + koff + ac0;

  // B per-lane fragment bases: row bn+wn+n*16+rl, col koff + sw*8 (+t*64+ks*32)
  const bf16* __restrict__ Bp[4];
#pragma unroll
  for (int n = 0; n < 4; ++n)
    Bp[n] = Wt + (size_t)(bn + wn + n * 16 + rl) * KTOT + koff + sw * 8;

  f32x4 acc[4][4] = {};
  float4 av[4];
  bf16x8 af[4][2], bA[4][2], bB[4][2];

#define ISSUE_AV1(tt)                                                         \
  { _Pragma("unroll")                                                         \
    for (int q = 0; q < 4; ++q)                                               \
      av[q] = *(const float4*)(Xrow + (tt) * 64 + q * 4); }

#define WRITE_A1(buf)                                                         \
  { bf16x8 w0, w1;                                                            \
    _Pragma("unroll")                                                         \
    for (int e = 0; e < 4; ++e) {                                             \
      w0[e]     = f2b(((const float*)&av[0])[e]);                             \
      w0[e + 4] = f2b(((const float*)&av[1])[e]);                             \
      w1[e]     = f2b(((const float*)&av[2])[e]);                             \
      w1[e + 4] = f2b(((const float*)&av[3])[e]);                             \
    }                                                                         \
    *(bf16x8*)(&A1[buf][arow * 64 + ((as0 ^ (arow & 7)) * 8)]) = w0;          \
    *(bf16x8*)(&A1[buf][arow * 64 + (((as0 + 1) ^ (arow & 7)) * 8)]) = w1; }

#define ISSUE_B1(SET, tt)                                                     \
  { _Pragma("unroll")                                                         \
    for (int n = 0; n < 4; ++n)                                               \
      _Pragma("unroll")                                                       \
      for (int ks = 0; ks < 2; ++ks)                                          \
        SET[n][ks] = *(const bf16x8*)(Bp[n] + (tt) * 64 + ks * 32); }

#define BODY1(CURB, NXTB, t)                                                  \
  { const int cur = (t) & 1;                                                  \
    _Pragma("unroll")                                                         \
    for (int m = 0; m < 4; ++m)                                               \
      _Pragma("unroll")                                                       \
      for (int ks = 0; ks < 2; ++ks)                                          \
        af[m][ks] = *(const bf16x8*)(&A1[cur][(wm + m * 16 + rl) * 64 +       \
                                              (((ks * 4 + sw) ^ sx) * 8)]);   \
    cfence();                                                                 \
    if ((t) + 1 < 8) ISSUE_B1(NXTB, (t) + 1);                                 \
    cfence();                                                                 \
    asm volatile("s_waitcnt lgkmcnt(0)" ::: "memory");                        \
    __builtin_amdgcn_sched_barrier(0);                                        \
    __builtin_amdgcn_s_setprio(1);                                            \
    _Pragma("unroll")                                                         \
    for (int m = 0; m < 4; ++m)                                               \
      _Pragma("unroll")                                                       \
      for (int n = 0; n < 4; ++n)                                             \
        _Pragma("unroll")                                                     \
        for (int ks = 0; ks < 2; ++ks)                                        \
          acc[m][n] = __builtin_amdgcn_mfma_f32_16x16x32_bf16(                \
              af[m][ks], CURB[n][ks], acc[m][n], 0, 0, 0);                    \
    __builtin_amdgcn_s_setprio(0);                                            \
    if ((t) + 1 < 8) {                                                        \
      asm volatile("s_waitcnt vmcnt(8)" ::: "memory");                        \
      WRITE_A1(cur ^ 1);                                                      \
      if ((t) + 2 < 8) ISSUE_AV1((t) + 2);                                    \
      asm volatile("s_waitcnt lgkmcnt(0)" ::: "memory");                      \
      bar();                                                                  \
      if ((t) + 2 < 8) asm volatile("s_waitcnt vmcnt(4)" ::: "memory");       \
      else             asm volatile("s_waitcnt vmcnt(0)" ::: "memory");       \
    } }

  // prologue
  ISSUE_AV1(0);
  asm volatile("s_waitcnt vmcnt(0)" ::: "memory");
  WRITE_A1(0);
  ISSUE_B1(bA, 0);
  ISSUE_AV1(1);
  asm volatile("s_waitcnt lgkmcnt(0)" ::: "memory");
  bar();
  asm volatile("s_waitcnt vmcnt(4)" ::: "memory");   // B(0) landed, av(1) in flight

  for (int t2 = 0; t2 < 8; t2 += 2) {
    BODY1(bA, bB, t2);
    BODY1(bB, bA, t2 + 1);
  }
#undef BODY1
#undef ISSUE_B1
#undef WRITE_A1
#undef ISSUE_AV1

  // epilogue: per-wave 64x64 transpose via scr -> contiguous bf16x8 stores
  float* scr = scr_ + wave * (16 * 68);
#pragma unroll
  for (int m = 0; m < 4; ++m) {
    int grow = bm + wm + m * 16;
#pragma unroll
    for (int n = 0; n < 4; ++n)
#pragma unroll
      for (int j = 0; j < 4; ++j)
        scr[(sw * 4 + j) * 68 + n * 16 + rl] = acc[m][n][j];
    asm volatile("s_waitcnt lgkmcnt(0)" ::: "memory");
#pragma unroll
    for (int p = 0; p < 2; ++p) {
      int row = p * 8 + (lane >> 3);
      int col8 = (lane & 7) * 8;
      f32x4 a = *(const f32x4*)(scr + row * 68 + col8);
      f32x4 b = *(const f32x4*)(scr + row * 68 + col8 + 4);
      bf16x8 o;
#pragma unroll
      for (int e = 0; e < 4; ++e) { o[e] = f2b(a[e]); o[e + 4] = f2b(b[e]); }
      *(bf16x8*)(&Pc[(size_t)(grow + row) * NOUT + bn + wn + col8]) = o;
    }
    asm volatile("s_waitcnt lgkmcnt(0)" ::: "memory");
  }
}

// ---------------------------------------------------------------------------
// GEMM2: out = z @ wuT^T + b_up -> f32. Tile 128x256, BK=64, nt=8.
// Same structure as gemm1f: B (wuT) direct-to-reg dbuf; A (z, bf16) reg-staged
// -> LDS dbuf (2x 16B loads/thread, no cvt). 1 barrier/iter.
// Ledger: [az(t+1)x2, B(t+1)x8] -> mid vmcnt(8); end vmcnt(2).
// grid 512: xcd owns 8 row-tiles x all 8 col-tiles (z slice 1MB + wuT 2MB L2).
// ---------------------------------------------------------------------------
__global__ __launch_bounds__(512, 2)
void gemm2(const bf16* __restrict__ Z, const bf16* __restrict__ Bt,
           const float* __restrict__ bu, float* __restrict__ OUT) {
  constexpr int LDA = 512, LDB = 512, N = 2048;
  __shared__ bf16 A2[2][128 * 64];     // 32 KB
  __shared__ float scr_[8 * 16 * 68];  // 34.8 KB

  const int bid = blockIdx.x;
  const int xcd = bid & 7, w = bid >> 3;      // w 0..63
  const int bx = xcd * 8 + (w & 7);           // 0..63 row tile (128 rows)
  const int by = w >> 3;                      // 0..7 col tile (256 cols)
  const int bm = bx * 128;
  const int bn = by * 256;

  const int tid = threadIdx.x, lane = tid & 63, wave = tid >> 6;
  const int wm = (wave >> 2) * 64;
  const int wn = (wave & 3) * 64;
  const int rl = lane & 15, sw = lane >> 4, sx = rl & 7;

  const int arow = tid >> 2, ac0 = (tid & 3) * 16, as0 = (tid & 3) * 2;
  const bf16* __restrict__ Zrow = Z + (size_t)(bm + arow) * LDA + ac0;

  const bf16* __restrict__ Bp[4];
#pragma unroll
  for (int n = 0; n < 4; ++n)
    Bp[n] = Bt + (size_t)(bn + wn + n * 16 + rl) * LDB + sw * 8;

  f32x4 acc[4][4] = {};
  bf16x8 az0, az1;
  bf16x8 af[4][2], bA[4][2], bB[4][2];

#define ISSUE_AZ(tt)                                                          \
  { az0 = *(const bf16x8*)(Zrow + (tt) * 64);                                 \
    az1 = *(const bf16x8*)(Zrow + (tt) * 64 + 8); }

#define WRITE_A2(buf)                                                         \
  { *(bf16x8*)(&A2[buf][arow * 64 + ((as0 ^ (arow & 7)) * 8)]) = az0;         \
    *(bf16x8*)(&A2[buf][arow * 64 + (((as0 + 1) ^ (arow & 7)) * 8)]) = az1; }

#define ISSUE_B2(SET, tt)                                                     \
  { _Pragma("unroll")                                                         \
    for (int n = 0; n < 4; ++n)                                               \
      _Pragma("unroll")                                                       \
      for (int ks = 0; ks < 2; ++ks)                                          \
        SET[n][ks] = *(const bf16x8*)(Bp[n] + (tt) * 64 + ks * 32); }

#define BODY2(CURB, NXTB, t)                                                  \
  { const int cur = (t) & 1;                                                  \
    _Pragma("unroll")                                                         \
    for (int m = 0; m < 4; ++m)                                               \
      _Pragma("unroll")                                                       \
      for (int ks = 0; ks < 2; ++ks)                                          \
        af[m][ks] = *(const bf16x8*)(&A2[cur][(wm + m * 16 + rl) * 64 +       \
                                              (((ks * 4 + sw) ^ sx) * 8)]);   \
    cfence();                                                                 \
    if ((t) + 1 < 8) ISSUE_B2(NXTB, (t) + 1);                                 \
    cfence();                                                                 \
    asm volatile("s_waitcnt lgkmcnt(0)" ::: "memory");                        \
    __builtin_amdgcn_sched_barrier(0);                                        \
    __builtin_amdgcn_s_setprio(1);                                            \
    _Pragma("unroll")                                                         \
    for (int m = 0; m < 4; ++m)                                               \
      _Pragma("unroll")                                                       \
      for (int n = 0; n < 4; ++n)                                             \
        _Pragma("unroll")                                                     \
        for (int ks = 0; ks < 2; ++ks)                                        \
          acc[m][n] = __builtin_amdgcn_mfma_f32_16x16x32_bf16(                \
              af[m][ks], CURB[n][ks], acc[m][n], 0, 0, 0);                    \
    __builtin_amdgcn_s_setprio(0);                                            \
    if ((t) + 1 < 8) {                                                        \
      asm volatile("s_waitcnt vmcnt(8)" ::: "memory");                        \
      WRITE_A2(cur ^ 1);                                                      \
      if ((t) + 2 < 8) ISSUE_AZ((t) + 2);                                     \
      asm volatile("s_waitcnt lgkmcnt(0)" ::: "memory");                      \
      bar();                                                                  \
      if ((t) + 2 < 8) asm volatile("s_waitcnt vmcnt(2)" ::: "memory");       \
      else             asm volatile("s_waitcnt vmcnt(0)" ::: "memory");       \
    } }

  // prologue
  ISSUE_AZ(0);
  asm volatile("s_waitcnt vmcnt(0)" ::: "memory");
  WRITE_A2(0);
  ISSUE_B2(bA, 0);
  ISSUE_AZ(1);
  asm volatile("s_waitcnt lgkmcnt(0)" ::: "memory");
  bar();
  asm volatile("s_waitcnt vmcnt(2)" ::: "memory");   // B(0) landed, az(1) in flight

  for (int t2 = 0; t2 < 8; t2 += 2) {
    BODY2(bA, bB, t2);
    BODY2(bB, bA, t2 + 1);
  }
#undef BODY2
#undef ISSUE_B2
#undef WRITE_A2
#undef ISSUE_AZ

  // epilogue: per-wave 64x64 f32 transpose -> nontemporal f32x4 stores
  float* scr = scr_ + wave * (16 * 68);
  const int r4 = lane >> 4, c4 = lane & 15;
#pragma unroll
  for (int m = 0; m < 4; ++m) {
    int grow = bm + wm + m * 16;
#pragma unroll
    for (int n = 0; n < 4; ++n)
#pragma unroll
      for (int j = 0; j < 4; ++j)
        scr[(sw * 4 + j) * 68 + n * 16 + rl] =
            acc[m][n][j] + bu[bn + wn + n * 16 + rl];
    asm volatile("s_waitcnt lgkmcnt(0)" ::: "memory");
#pragma unroll
    for (int jj = 0; jj < 4; ++jj) {
      int row = jj * 4 + r4;
      f32x4 v = *(const f32x4*)(scr + row * 68 + c4 * 4);
      __builtin_nontemporal_store(
          v, (f32x4*)(&OUT[(size_t)(grow + row) * N + bn + wn + c4 * 4]));
    }
    asm volatile("s_waitcnt lgkmcnt(0)" ::: "memory");
  }
}

// ---------------------------------------------------------------------------
extern "C" void kernel_launch(void* const* d_in, const int* in_sizes, int n_in,
                              void* d_out, int out_size, void* d_ws, size_t ws_size,
                              hipStream_t stream) {
  const float* x      = (const float*)d_in[0];   // [8192,2048]
  const float* phm    = (const float*)d_in[1];   // [4,4,4]
  const float* W_down = (const float*)d_in[2];   // [4,512,128]
  const float* b_down = (const float*)d_in[3];   // [512]
  const float* W_up   = (const float*)d_in[4];   // [4,128,512]
  const float* b_up   = (const float*)d_in[5];   // [2048]
  float* out = (float*)d_out;                    // [8192,2048] f32

  const int T = 8192, B = 512;
  const size_t MB = 1024 * 1024;

  char* ws = (char*)d_ws;
  bf16* wdT = (bf16*)(ws);                 //  2 MB  [512][2048]
  bf16* wuT = (bf16*)(ws + 2 * MB);        //  2 MB  [2048][512]
  bf16* z   = (bf16*)(ws + 4 * MB);        //  8 MB  [8192][512]
  bf16* P   = (bf16*)(ws + 12 * MB);       // 32 MB  4 x [8192][512] partials

  build_w<<<dim3((2 * 1024 * 1024) / 256), dim3(256), 0, stream>>>(
      phm, W_down, W_up, wdT, wuT);

  // P[ch] = x(f32) @ wdT (chunk ch), cast fused. grid 512
  gemm1f<<<dim3(512), dim3(512), 0, stream>>>(x, wdT, P);

  // z = relu(sum P + b_down)
  zred<<<dim3(T * B / 8 / 256), dim3(256), 0, stream>>>(P, b_down, z);

  // out = z @ wuT + b_up. grid 512
  gemm2<<<dim3(512), dim3(512), 0, stream>>>(z, wuT, b_up, out);
}